// Round 5
// baseline (140.195 us; speedup 1.0000x reference)
//
#include <hip/hip_runtime.h>
#include <math.h>

#define BINS 30
#define BLOCK 256
#define UNROLL 4                        // float4-batches per thread
#define EPT (UNROLL * 4)                // 16 elements per thread
#define EPB (BLOCK * EPT)               // 4096 elements per block
#define NWAVES 4
#define CPW 16                          // histogram copies per wave (lane & 15)
#define NCOPIES (NWAVES * CPW)          // 64 copies / block
#define CSTRIDE 31                      // words per copy: 30 bins + pad (bank stagger)
#define GSCALE 32768.0f                 // g in 0.15 fixed point, bits 0..22
#define CNT_ONE (2u << 23)              // +2 per element, count in bits 23..31
#define GMASK 0x7FFFFFu

// d_ws layout: [0..29] u32 counts, [30..59] f32 g-sums

__device__ __forceinline__ void ghmc_elem(float p, int t, unsigned int* s_hist,
                                          unsigned int copy_base)
{
    // g = |sigmoid(p) - t| = sigmoid(t ? -p : p)
    float q = __int_as_float(__float_as_int(p) ^ (t << 31));
    float e = __expf(-q);
    float g = __builtin_amdgcn_rcpf(1.0f + e);
    int b = min((int)(g * 30.0f), BINS - 1);
    unsigned int pkt = CNT_ONE | (unsigned int)(g * GSCALE);
    atomicAdd(&s_hist[copy_base + b], pkt);
}

__global__ __launch_bounds__(BLOCK) void ghmc_pass1(
    const float* __restrict__ pred, const int* __restrict__ target,
    unsigned int* __restrict__ g_cnt, float* __restrict__ g_gsum,
    int nb4, int n)   // nb4 = number of float4s covered by the batched part
{
    __shared__ unsigned int s_hist[NCOPIES * CSTRIDE];

    const int tid = threadIdx.x;
    const unsigned int copy_base = (((tid >> 6) << 4) + (tid & (CPW - 1))) * CSTRIDE;

    for (int i = tid; i < NCOPIES * CSTRIDE; i += BLOCK)
        s_hist[i] = 0u;
    __syncthreads();

    // ---- batched main part: 8 loads issued back-to-back, then consumed ----
    const int base = blockIdx.x * (BLOCK * UNROLL) + tid;   // float4 index
    const float4* p4 = reinterpret_cast<const float4*>(pred);
    const int4*   t4 = reinterpret_cast<const int4*>(target);

    float4 pv[UNROLL];
    int4   tv[UNROLL];
    #pragma unroll
    for (int u = 0; u < UNROLL; ++u) {
        pv[u] = p4[base + u * BLOCK];
        tv[u] = t4[base + u * BLOCK];
    }
    #pragma unroll
    for (int u = 0; u < UNROLL; ++u) {
        ghmc_elem(pv[u].x, tv[u].x, s_hist, copy_base);
        ghmc_elem(pv[u].y, tv[u].y, s_hist, copy_base);
        ghmc_elem(pv[u].z, tv[u].z, s_hist, copy_base);
        ghmc_elem(pv[u].w, tv[u].w, s_hist, copy_base);
    }

    // ---- scalar tail (elements beyond nb4*4) — block 0 only; empty for N=2^24 ----
    if (blockIdx.x == 0) {
        for (int i = nb4 * 4 + tid; i < n; i += BLOCK)
            ghmc_elem(pred[i], target[i], s_hist, copy_base);
    }

    __syncthreads();
    if (tid < BINS) {
        unsigned int cnt = 0;
        float gs = 0.0f;
        #pragma unroll
        for (int c = 0; c < NCOPIES; ++c) {
            unsigned int v = s_hist[c * CSTRIDE + tid];
            cnt += v >> 23;
            gs  += (float)(v & GMASK);
        }
        atomicAdd(&g_cnt[tid], cnt);
        atomicAdd(&g_gsum[tid], gs * (1.0f / GSCALE));
    }
}

__global__ __launch_bounds__(64) void ghmc_final(
    const unsigned int* __restrict__ counts, const float* __restrict__ gsums,
    const float* __restrict__ acc_sum, float* __restrict__ out, float total)
{
    const int tid = threadIdx.x;  // one wave of 64
    bool nonempty = (tid < BINS) && (counts[tid] > 0u);
    float n = fmaxf((float)__popcll(__ballot(nonempty)), 1.0f);

    float val = 0.0f;
    if (nonempty) {
        float c     = (float)counts[tid];   // = 2 * elements (reference histogram)
        float elems = 0.5f * c;
        float gmean = gsums[tid] / elems;
        // two-channel bce per element collapses to F(g); evaluate at bin mean
        float F = log1pf(expf(gmean)) + log1pf(expf(1.0f - gmean)) - 1.0f + gmean;
        float new_acc = 0.75f * acc_sum[tid] + 0.25f * c;
        float w = (total / fmaxf(new_acc, 1e-12f)) / n;
        val = w * elems * F;
    }
    #pragma unroll
    for (int off = 32; off > 0; off >>= 1) val += __shfl_down(val, off);
    if (tid == 0) out[0] = val / total;
}

extern "C" void kernel_launch(void* const* d_in, const int* in_sizes, int n_in,
                              void* d_out, int out_size, void* d_ws, size_t ws_size,
                              hipStream_t stream) {
    const float* pred    = (const float*)d_in[0];
    const float* acc_sum = (const float*)d_in[1];
    const int*   target  = (const int*)d_in[2];
    float* out = (float*)d_out;

    int n = in_sizes[0];
    float total = fmaxf(2.0f * (float)n, 1.0f);

    int grid = n / EPB;                 // full batches (4096 for N=2^24)
    if (grid < 1) grid = 1;
    int nb4 = (n >= EPB) ? grid * (BLOCK * UNROLL) : 0;  // float4s covered by batches

    unsigned int* g_cnt  = (unsigned int*)d_ws;
    float*        g_gsum = (float*)d_ws + BINS;

    hipMemsetAsync(d_ws, 0, 2 * BINS * sizeof(float), stream);

    ghmc_pass1<<<grid, BLOCK, 0, stream>>>(pred, target, g_cnt, g_gsum, nb4, n);
    ghmc_final<<<1, 64, 0, stream>>>(g_cnt, g_gsum, acc_sum, out, total);
}

// Round 6
// 83.566 us; speedup vs baseline: 1.6776x; 1.6776x over previous
//
#include <hip/hip_runtime.h>
#include <math.h>

#define BINS 30
#define BLOCK 256
#define GRID 2048
#define ITERS 8                         // fast path: n4 == GRID*BLOCK*ITERS
#define CPW 16                          // histogram copies per wave (lane & 15)
#define NCOPIES 64                      // 4 waves * 16
#define CSTRIDE 31                      // 30 bins + 1 pad word (bank stagger)
#define GSCALE 32768.0f                 // g in 0.15 fixed point, bits 0..22
#define CNT_ONE (2u << 23)              // +2 per element, count in bits 23..31
#define GMASK 0x7FFFFFu

// d_ws layout: [0..29] u32 counts, [30..59] f32 g-sums

__device__ __forceinline__ void ghmc_elem(float p, int t, unsigned int* s_hist,
                                          unsigned int copy_base)
{
    // g = |sigmoid(p) - t| = sigmoid(t ? -p : p)
    float q = __int_as_float(__float_as_int(p) ^ (t << 31));
    float e = __expf(-q);
    float g = __builtin_amdgcn_rcpf(1.0f + e);
    int b = min((int)(g * 30.0f), BINS - 1);
    unsigned int pkt = CNT_ONE | (unsigned int)(g * GSCALE);
    atomicAdd(&s_hist[copy_base + b], pkt);
}

__device__ __forceinline__ void ghmc_vec4(float4 p, int4 t, unsigned int* s_hist,
                                          unsigned int copy_base)
{
    ghmc_elem(p.x, t.x, s_hist, copy_base);
    ghmc_elem(p.y, t.y, s_hist, copy_base);
    ghmc_elem(p.z, t.z, s_hist, copy_base);
    ghmc_elem(p.w, t.w, s_hist, copy_base);
}

__device__ __forceinline__ void hist_init(unsigned int* s_hist, int tid)
{
    for (int i = tid; i < NCOPIES * CSTRIDE; i += BLOCK) s_hist[i] = 0u;
}

__device__ __forceinline__ void hist_flush(unsigned int* s_hist, int tid,
                                           unsigned int* g_cnt, float* g_gsum)
{
    if (tid < BINS) {
        unsigned int cnt = 0;
        float gs = 0.0f;
        #pragma unroll
        for (int c = 0; c < NCOPIES; ++c) {
            unsigned int v = s_hist[c * CSTRIDE + tid];
            cnt += v >> 23;
            gs  += (float)(v & GMASK);
        }
        atomicAdd(&g_cnt[tid], cnt);
        atomicAdd(&g_gsum[tid], gs * (1.0f / GSCALE));
    }
}

// ---- fast path: exact N = GRID*BLOCK*4*ITERS, 3-deep register pipeline ----
__global__ __launch_bounds__(BLOCK) void ghmc_pass1_pipe(
    const float* __restrict__ pred, const int* __restrict__ target,
    unsigned int* __restrict__ g_cnt, float* __restrict__ g_gsum)
{
    __shared__ unsigned int s_hist[NCOPIES * CSTRIDE];
    const int tid = threadIdx.x;
    const unsigned int copy_base = (((tid >> 6) << 4) + (tid & (CPW - 1))) * CSTRIDE;
    hist_init(s_hist, tid);
    __syncthreads();

    const float4* p4 = reinterpret_cast<const float4*>(pred);
    const int4*   t4 = reinterpret_cast<const int4*>(target);
    const int stride = GRID * BLOCK;
    const int idx = blockIdx.x * BLOCK + tid;

    float4 pv[3];
    int4   tv[3];
    #pragma unroll
    for (int k = 0; k < 3; ++k) {
        pv[k] = p4[idx + k * stride];
        tv[k] = t4[idx + k * stride];
    }
    __builtin_amdgcn_sched_barrier(0);   // keep prologue loads hoisted

    #pragma unroll
    for (int k = 0; k < ITERS; ++k) {
        const int slot = k % 3;          // compile-time after full unroll
        ghmc_vec4(pv[slot], tv[slot], s_hist, copy_base);
        if (k + 3 < ITERS) {             // refill: lands 3 iterations later
            pv[slot] = p4[idx + (k + 3) * stride];
            tv[slot] = t4[idx + (k + 3) * stride];
        }
    }

    __syncthreads();
    hist_flush(s_hist, tid, g_cnt, g_gsum);
}

// ---- generic fallback: any n ----
__global__ __launch_bounds__(BLOCK) void ghmc_pass1_gen(
    const float* __restrict__ pred, const int* __restrict__ target,
    unsigned int* __restrict__ g_cnt, float* __restrict__ g_gsum,
    int n4, int n)
{
    __shared__ unsigned int s_hist[NCOPIES * CSTRIDE];
    const int tid = threadIdx.x;
    const unsigned int copy_base = (((tid >> 6) << 4) + (tid & (CPW - 1))) * CSTRIDE;
    hist_init(s_hist, tid);
    __syncthreads();

    const int gid    = blockIdx.x * BLOCK + tid;
    const int stride = gridDim.x * BLOCK;
    for (int i = gid; i < n4; i += stride) {
        float4 p = reinterpret_cast<const float4*>(pred)[i];
        int4   t = reinterpret_cast<const int4*>(target)[i];
        ghmc_vec4(p, t, s_hist, copy_base);
    }
    if (blockIdx.x == 0) {
        for (int i = n4 * 4 + tid; i < n; i += BLOCK)
            ghmc_elem(pred[i], target[i], s_hist, copy_base);
    }

    __syncthreads();
    hist_flush(s_hist, tid, g_cnt, g_gsum);
}

__global__ __launch_bounds__(64) void ghmc_final(
    const unsigned int* __restrict__ counts, const float* __restrict__ gsums,
    const float* __restrict__ acc_sum, float* __restrict__ out, float total)
{
    const int tid = threadIdx.x;  // one wave of 64
    bool nonempty = (tid < BINS) && (counts[tid] > 0u);
    float n = fmaxf((float)__popcll(__ballot(nonempty)), 1.0f);

    float val = 0.0f;
    if (nonempty) {
        float c     = (float)counts[tid];   // = 2 * elements (reference histogram)
        float elems = 0.5f * c;
        float gmean = gsums[tid] / elems;
        // two-channel bce per element collapses to F(g); evaluate at bin mean
        float F = log1pf(expf(gmean)) + log1pf(expf(1.0f - gmean)) - 1.0f + gmean;
        float new_acc = 0.75f * acc_sum[tid] + 0.25f * c;
        float w = (total / fmaxf(new_acc, 1e-12f)) / n;
        val = w * elems * F;
    }
    #pragma unroll
    for (int off = 32; off > 0; off >>= 1) val += __shfl_down(val, off);
    if (tid == 0) out[0] = val / total;
}

extern "C" void kernel_launch(void* const* d_in, const int* in_sizes, int n_in,
                              void* d_out, int out_size, void* d_ws, size_t ws_size,
                              hipStream_t stream) {
    const float* pred    = (const float*)d_in[0];
    const float* acc_sum = (const float*)d_in[1];
    const int*   target  = (const int*)d_in[2];
    float* out = (float*)d_out;

    int n  = in_sizes[0];
    int n4 = n / 4;
    float total = fmaxf(2.0f * (float)n, 1.0f);

    unsigned int* g_cnt  = (unsigned int*)d_ws;
    float*        g_gsum = (float*)d_ws + BINS;

    hipMemsetAsync(d_ws, 0, 2 * BINS * sizeof(float), stream);

    if (n4 == GRID * BLOCK * ITERS && n % 4 == 0) {
        ghmc_pass1_pipe<<<GRID, BLOCK, 0, stream>>>(pred, target, g_cnt, g_gsum);
    } else {
        ghmc_pass1_gen<<<GRID, BLOCK, 0, stream>>>(pred, target, g_cnt, g_gsum, n4, n);
    }
    ghmc_final<<<1, 64, 0, stream>>>(g_cnt, g_gsum, acc_sum, out, total);
}